// Round 1
// baseline (1367.366 us; speedup 1.0000x reference)
//
#include <hip/hip_runtime.h>
#include <hip/hip_bf16.h>
#include <math.h>

#define B_   4
#define S_   2048
#define E_   256
#define H_   8
#define D_   32
#define FF_  1024
#define NTOK (B_*S_)   // 8192

// ---------------- QKV projection ----------------
// x: [B,S,E]; w*: [D,D]; q,k,v out: [B,H,S,D]
__global__ __launch_bounds__(256) void qkv_kernel(
    const float* __restrict__ x,
    const float* __restrict__ wq, const float* __restrict__ wk, const float* __restrict__ wv,
    float* __restrict__ q, float* __restrict__ k, float* __restrict__ v)
{
    __shared__ float wqs[D_*D_], wks[D_*D_], wvs[D_*D_];
    __shared__ float xs[E_];
    const int tid = threadIdx.x;
    for (int i = tid; i < D_*D_; i += 256) {
        wqs[i] = wq[i]; wks[i] = wk[i]; wvs[i] = wv[i];
    }
    const int h = tid >> 5, d = tid & 31;
    const int tok0 = blockIdx.x * 16;
    for (int t = 0; t < 16; ++t) {
        const int tok = tok0 + t;
        __syncthreads();
        xs[tid] = x[(size_t)tok*E_ + tid];
        __syncthreads();
        float aq = 0.f, ak = 0.f, av = 0.f;
        #pragma unroll
        for (int i = 0; i < D_; ++i) {
            const float xv = xs[h*D_ + i];
            aq += xv * wqs[i*D_ + d];
            ak += xv * wks[i*D_ + d];
            av += xv * wvs[i*D_ + d];
        }
        const int b = tok >> 11;      // / S_
        const int s = tok & (S_-1);
        const size_t o = ((size_t)(b*H_ + h)*S_ + s)*D_ + d;
        q[o] = aq; k[o] = ak; v[o] = av;
    }
}

// ---------------- Flash attention (fp32) ----------------
// q,k,v: [B,H,S,D]; mask: [B,1,1,S]; attn_out: [B,S,E]
// block = 256 threads = 4 waves; wave = 16 queries x 4 key-segments
__global__ __launch_bounds__(256) void attn_kernel(
    const float* __restrict__ q, const float* __restrict__ k, const float* __restrict__ v,
    const int* __restrict__ mask, float* __restrict__ attn_out)
{
    const int tid  = threadIdx.x;
    const int lane = tid & 63;
    const int wv_  = tid >> 6;        // wave in block: 0..3
    const int qloc = lane & 15;
    const int seg  = lane >> 4;       // 0..3 key segment
    const int bh    = blockIdx.x >> 5;    // 0..31  (B*H)
    const int qtile = blockIdx.x & 31;
    const int b = bh >> 3;
    const int h = bh & 7;
    const int sq = qtile*64 + wv_*16 + qloc;

    const float* qrow = q + ((size_t)bh*S_ + sq)*D_;
    float qr[D_];
    #pragma unroll
    for (int d = 0; d < D_; ++d) qr[d] = qrow[d];

    float m = -3.0e38f, l = 0.f;
    float acc[D_];
    #pragma unroll
    for (int d = 0; d < D_; ++d) acc[d] = 0.f;

    const float* kbase = k + (size_t)bh*S_*D_;
    const float* vbase = v + (size_t)bh*S_*D_;
    const int*   mrow  = mask + b*S_;

    const int k0 = seg * (S_/4), k1 = k0 + (S_/4);
    for (int kk = k0; kk < k1; ++kk) {
        const float* kr = kbase + (size_t)kk*D_;
        float sc = 0.f;
        #pragma unroll
        for (int d = 0; d < D_; ++d) sc += qr[d]*kr[d];
        sc *= 0.0625f;                     // 1/sqrt(E)=1/16
        if (mrow[kk] == 0) sc = -1e20f;
        const float mn = fmaxf(m, sc);
        const float scale = __expf(m - mn);
        const float p = __expf(sc - mn);
        l = l*scale + p;
        const float* vr = vbase + (size_t)kk*D_;
        #pragma unroll
        for (int d = 0; d < D_; ++d) acc[d] = acc[d]*scale + p*vr[d];
        m = mn;
    }
    // merge the 4 key segments (lane bits 4,5)
    #pragma unroll
    for (int off = 16; off <= 32; off <<= 1) {
        const float mo = __shfl_xor(m, off);
        const float lo = __shfl_xor(l, off);
        const float mn = fmaxf(m, mo);
        const float se = __expf(m - mn), so = __expf(mo - mn);
        l = l*se + lo*so;
        #pragma unroll
        for (int d = 0; d < D_; ++d) {
            const float ao = __shfl_xor(acc[d], off);
            acc[d] = acc[d]*se + ao*so;
        }
        m = mn;
    }
    const float inv = 1.0f / l;
    if (seg == 0) {
        float* o = attn_out + ((size_t)(b*S_ + sq))*E_ + h*D_;
        #pragma unroll
        for (int j = 0; j < 8; ++j) {
            float4 t4 = make_float4(acc[4*j+0]*inv, acc[4*j+1]*inv,
                                    acc[4*j+2]*inv, acc[4*j+3]*inv);
            *(float4*)(o + 4*j) = t4;
        }
    }
}

// ---------------- fp32 tiled GEMM, fused bias/relu/residual ----------------
// C[M,N] = op(A[M,K] @ W[K,N] + bias) (+ R)
// BM=BN=128, BK=16; 256 threads; 8x8 per thread in 4 quadrants
template<int RELU, int RESID>
__global__ __launch_bounds__(256) void gemm_kernel(
    const float* __restrict__ A, const float* __restrict__ W,
    const float* __restrict__ bias, const float* __restrict__ R,
    float* __restrict__ C, int M, int N, int K)
{
    __shared__ float As[16][128];
    __shared__ float Bs[16][128];
    const int tid = threadIdx.x;
    const int tx = tid & 15, ty = tid >> 4;
    const int bm = blockIdx.y, bn = blockIdx.x;

    float acc[8][8] = {};

    for (int kb = 0; kb < K; kb += 16) {
        #pragma unroll
        for (int t = 0; t < 2; ++t) {
            const int idx = tid + t*256;
            const int r = idx >> 2, c = (idx & 3) * 4;
            const float4 a4 = *(const float4*)(A + (size_t)(bm*128 + r)*K + kb + c);
            As[c+0][r] = a4.x; As[c+1][r] = a4.y; As[c+2][r] = a4.z; As[c+3][r] = a4.w;
            const int rb = idx >> 5, cb = (idx & 31) * 4;
            *(float4*)(&Bs[rb][cb]) = *(const float4*)(W + (size_t)(kb + rb)*N + bn*128 + cb);
        }
        __syncthreads();
        #pragma unroll
        for (int kk = 0; kk < 16; ++kk) {
            float a[8], b[8];
            *(float4*)(a+0) = *(const float4*)(&As[kk][tx*0 + ty*4]);
            *(float4*)(a+4) = *(const float4*)(&As[kk][64 + ty*4]);
            *(float4*)(b+0) = *(const float4*)(&Bs[kk][tx*4]);
            *(float4*)(b+4) = *(const float4*)(&Bs[kk][64 + tx*4]);
            #pragma unroll
            for (int i = 0; i < 8; ++i) {
                #pragma unroll
                for (int j = 0; j < 8; ++j) acc[i][j] += a[i]*b[j];
            }
        }
        __syncthreads();
    }

    #pragma unroll
    for (int qi = 0; qi < 2; ++qi) {
        #pragma unroll
        for (int i = 0; i < 4; ++i) {
            const int m = bm*128 + qi*64 + ty*4 + i;
            #pragma unroll
            for (int qj = 0; qj < 2; ++qj) {
                const int n = bn*128 + qj*64 + tx*4;
                float4 o;
                o.x = acc[qi*4+i][qj*4+0] + bias[n+0];
                o.y = acc[qi*4+i][qj*4+1] + bias[n+1];
                o.z = acc[qi*4+i][qj*4+2] + bias[n+2];
                o.w = acc[qi*4+i][qj*4+3] + bias[n+3];
                if (RELU) {
                    o.x = fmaxf(o.x, 0.f); o.y = fmaxf(o.y, 0.f);
                    o.z = fmaxf(o.z, 0.f); o.w = fmaxf(o.w, 0.f);
                }
                if (RESID) {
                    const float4 r4 = *(const float4*)(R + (size_t)m*N + n);
                    o.x += r4.x; o.y += r4.y; o.z += r4.z; o.w += r4.w;
                }
                *(float4*)(C + (size_t)m*N + n) = o;
            }
        }
    }
}

// ---------------- series decomposition over E (window 25, edge pad) ----------------
__global__ __launch_bounds__(256) void decomp_kernel(
    const float* __restrict__ in, float* __restrict__ out)
{
    __shared__ float r[E_];
    const int row = blockIdx.x, e = threadIdx.x;
    const float xv = in[(size_t)row*E_ + e];
    r[e] = xv;
    __syncthreads();
    float sum = 0.f;
    #pragma unroll
    for (int j = -12; j <= 12; ++j) {
        int idx = e + j;
        idx = idx < 0 ? 0 : (idx > E_-1 ? E_-1 : idx);
        sum += r[idx];
    }
    out[(size_t)row*E_ + e] = xv - sum * (1.0f/25.0f);
}

extern "C" void kernel_launch(void* const* d_in, const int* in_sizes, int n_in,
                              void* d_out, int out_size, void* d_ws, size_t ws_size,
                              hipStream_t stream) {
    const float* x     = (const float*)d_in[0];
    const int*   mask  = (const int*)  d_in[1];
    const float* wq    = (const float*)d_in[2];
    const float* wk    = (const float*)d_in[3];
    const float* wv    = (const float*)d_in[4];
    const float* w_out = (const float*)d_in[5];
    const float* b_out = (const float*)d_in[6];
    const float* ff_w1 = (const float*)d_in[7];
    const float* ff_b1 = (const float*)d_in[8];
    const float* ff_w2 = (const float*)d_in[9];
    const float* ff_b2 = (const float*)d_in[10];
    const float* pr_w1 = (const float*)d_in[11];
    const float* pr_b1 = (const float*)d_in[12];
    const float* pr_w2 = (const float*)d_in[13];
    const float* pr_b2 = (const float*)d_in[14];
    float* out = (float*)d_out;

    char* ws = (char*)d_ws;
    const size_t MB = 1024ull*1024ull;
    float* q        = (float*)(ws + 0*MB);    // 8MB
    float* kbuf     = (float*)(ws + 8*MB);    // 8MB
    float* vbuf     = (float*)(ws + 16*MB);   // 8MB
    float* attn_out = (float*)(ws + 24*MB);   // 8MB
    float* x1       = (float*)(ws + 32*MB);   // 8MB
    float* y        = (float*)(ws + 40*MB);   // 8MB
    float* h1       = (float*)(ws + 0*MB);    // 32MB (reuses q,k,v,attn_out — dead by then)
    float* s        = (float*)(ws + 32*MB);   // reuses x1
    float* s2       = (float*)(ws + 40*MB);   // reuses y
    float* h2       = (float*)(ws + 0*MB);    // reuses h1

    // 1. QKV
    qkv_kernel<<<NTOK/16, 256, 0, stream>>>(x, wq, wk, wv, q, kbuf, vbuf);
    // 2. attention
    attn_kernel<<<(B_*H_*S_)/64, 256, 0, stream>>>(q, kbuf, vbuf, mask, attn_out);
    // 3. out-proj + residual: x1 = x + attn_out @ w_out + b_out
    dim3 gE(E_/128, NTOK/128);
    gemm_kernel<0,1><<<gE, 256, 0, stream>>>(attn_out, w_out, b_out, x, x1, NTOK, E_, E_);
    // 4. decomposition 1
    decomp_kernel<<<NTOK, 256, 0, stream>>>(x1, y);
    // 5. FFN
    dim3 gF(FF_/128, NTOK/128);
    gemm_kernel<1,0><<<gF, 256, 0, stream>>>(y, ff_w1, ff_b1, nullptr, h1, NTOK, FF_, E_);
    gemm_kernel<0,1><<<gE, 256, 0, stream>>>(h1, ff_w2, ff_b2, y, s, NTOK, E_, FF_);
    // 6. decomposition 2
    decomp_kernel<<<NTOK, 256, 0, stream>>>(s, s2);
    // 7. projection FFN -> out
    gemm_kernel<1,0><<<gF, 256, 0, stream>>>(s2, pr_w1, pr_b1, nullptr, h2, NTOK, FF_, E_);
    gemm_kernel<0,0><<<gE, 256, 0, stream>>>(h2, pr_w2, pr_b2, nullptr, out, NTOK, E_, FF_);
}

// Round 2
// 534.018 us; speedup vs baseline: 2.5605x; 2.5605x over previous
//
#include <hip/hip_runtime.h>
#include <hip/hip_bf16.h>
#include <math.h>

#define B_   4
#define S_   2048
#define E_   256
#define H_   8
#define D_   32
#define FF_  1024
#define NTOK (B_*S_)   // 8192

typedef __attribute__((ext_vector_type(8))) short short8;
typedef __attribute__((ext_vector_type(4))) float f32x4;
typedef __attribute__((ext_vector_type(4))) unsigned u32x4;
typedef __hip_bfloat16 bf16;

// ---------------- QKV projection -> bf16 [B,H,S,D] ----------------
__global__ __launch_bounds__(256) void qkv_kernel(
    const float* __restrict__ x,
    const float* __restrict__ wq, const float* __restrict__ wk, const float* __restrict__ wv,
    bf16* __restrict__ q, bf16* __restrict__ k, bf16* __restrict__ v)
{
    __shared__ float wqs[D_*D_], wks[D_*D_], wvs[D_*D_];
    __shared__ float xs[E_];
    const int tid = threadIdx.x;
    for (int i = tid; i < D_*D_; i += 256) {
        wqs[i] = wq[i]; wks[i] = wk[i]; wvs[i] = wv[i];
    }
    const int h = tid >> 5, d = tid & 31;
    const int tok0 = blockIdx.x * 16;
    for (int t = 0; t < 16; ++t) {
        const int tok = tok0 + t;
        __syncthreads();
        xs[tid] = x[(size_t)tok*E_ + tid];
        __syncthreads();
        float aq = 0.f, ak = 0.f, av = 0.f;
        #pragma unroll
        for (int i = 0; i < D_; ++i) {
            const float xv = xs[h*D_ + i];
            aq += xv * wqs[i*D_ + d];
            ak += xv * wks[i*D_ + d];
            av += xv * wvs[i*D_ + d];
        }
        const int b = tok >> 11;
        const int s = tok & (S_-1);
        const size_t o = ((size_t)(b*H_ + h)*S_ + s)*D_ + d;
        q[o] = __float2bfloat16(aq);
        k[o] = __float2bfloat16(ak);
        v[o] = __float2bfloat16(av);
    }
}

// ---------------- V transpose: [B,H,S,D] -> VT [B,H,D,S] ----------------
__global__ __launch_bounds__(256) void vtrans_kernel(
    const short* __restrict__ v, short* __restrict__ vt)
{
    __shared__ short t2[D_][256];   // [d][s-chunk]
    const int tid = threadIdx.x;
    const int bh = blockIdx.x >> 3;
    const int s0 = (blockIdx.x & 7) * 256;
    const short* src = v + ((size_t)bh*S_ + s0 + tid)*D_;
    const short8 r0 = *(const short8*)(src);
    const short8 r1 = *(const short8*)(src + 8);
    const short8 r2 = *(const short8*)(src + 16);
    const short8 r3 = *(const short8*)(src + 24);
    #pragma unroll
    for (int i = 0; i < 8; ++i) {
        t2[i     ][tid] = r0[i];
        t2[i + 8 ][tid] = r1[i];
        t2[i + 16][tid] = r2[i];
        t2[i + 24][tid] = r3[i];
    }
    __syncthreads();
    const int d = tid >> 3, j = tid & 7;
    short* dst = vt + ((size_t)(bh*D_ + d))*S_ + s0 + j*32;
    const short8* row = (const short8*)&t2[d][j*32];
    const short8 o0 = row[0], o1 = row[1], o2 = row[2], o3 = row[3];
    *(short8*)(dst     ) = o0;
    *(short8*)(dst + 8 ) = o1;
    *(short8*)(dst + 16) = o2;
    *(short8*)(dst + 24) = o3;
}

// ---------------- MFMA flash attention ----------------
// scores^T = mfma(A=K_tile[16k x 32d], B=Q^T) ; C: col=lane&15=query, row=(lane>>4)*4+r=key
// PV:       OT  = mfma(A=VT[16d x 32k],  B=P) ; P B-frag built in-register via shfl exchange
__device__ __forceinline__ unsigned pack2_bf16(float a, float b) {
    unsigned ua = __builtin_bit_cast(unsigned, a);
    unsigned ub = __builtin_bit_cast(unsigned, b);
    ua = (ua + 0x7fffu + ((ua >> 16) & 1u)) >> 16;
    ub = (ub + 0x7fffu + ((ub >> 16) & 1u)) >> 16;
    return ua | (ub << 16);
}

__global__ __launch_bounds__(256) void attn_mfma_kernel(
    const short* __restrict__ qg, const short* __restrict__ kg,
    const short* __restrict__ vtg, const int* __restrict__ mask,
    float* __restrict__ attn_out)
{
    const int lane = threadIdx.x & 63;
    const int wid  = threadIdx.x >> 6;
    const int col  = lane & 15;      // query col (B,C); row for A-frags
    const int grp  = lane >> 4;      // 0..3
    const int bh   = (int)blockIdx.x >> 5;
    const int qt   = (int)blockIdx.x & 31;
    const int b    = bh >> 3;
    const int h    = bh & 7;
    const int q0   = qt*64 + wid*16;

    const short8 qf = *(const short8*)(qg + ((size_t)bh*S_ + q0 + col)*D_ + grp*8);
    const short* kbase = kg  + (size_t)bh*S_*D_;
    const short* vbase = vtg + (size_t)bh*D_*S_;
    const int*   mrow  = mask + b*S_;

    f32x4 ot0 = {0.f,0.f,0.f,0.f}, ot1 = {0.f,0.f,0.f,0.f};
    const f32x4 zero = {0.f,0.f,0.f,0.f};
    float m = -3.0e38f, l = 0.f;

    for (int k0 = 0; k0 < S_; k0 += 64) {
        // ---- scores^T (4 x 16-key blocks) ----
        f32x4 s[4];
        #pragma unroll
        for (int t = 0; t < 4; ++t) {
            const short8 kf = *(const short8*)(kbase + (size_t)(k0 + t*16 + col)*D_ + grp*8);
            s[t] = __builtin_amdgcn_mfma_f32_16x16x32_bf16(kf, qf, zero, 0, 0, 0);
        }
        // ---- mask + scale, row max ----
        float sc[4][4];
        float pmax = -3.0e38f;
        #pragma unroll
        for (int t = 0; t < 4; ++t) {
            #pragma unroll
            for (int r = 0; r < 4; ++r) {
                float z = s[t][r] * 0.0625f;               // 1/sqrt(E)
                if (mrow[k0 + t*16 + grp*4 + r] == 0) z = -1e20f;
                sc[t][r] = z;
                pmax = fmaxf(pmax, z);
            }
        }
        pmax = fmaxf(pmax, __shfl_xor(pmax, 16));
        pmax = fmaxf(pmax, __shfl_xor(pmax, 32));
        // ---- online-softmax update (defer-max, THR=8) ----
        if (!__all(pmax - m <= 8.0f)) {
            const float mn = fmaxf(m, pmax);
            const float al = __expf(m - mn);
            l *= al;
            #pragma unroll
            for (int r = 0; r < 4; ++r) { ot0[r] *= al; ot1[r] *= al; }
            m = mn;
        }
        float ps = 0.f;
        #pragma unroll
        for (int t = 0; t < 4; ++t) {
            #pragma unroll
            for (int r = 0; r < 4; ++r) {
                sc[t][r] = __expf(sc[t][r] - m);
                ps += sc[t][r];
            }
        }
        ps += __shfl_xor(ps, 16);
        ps += __shfl_xor(ps, 32);
        l += ps;
        // ---- pack P to bf16 pairs; keys of pk[t][i] = {t*16+4g+2i, +1} ----
        unsigned pk[4][2];
        #pragma unroll
        for (int t = 0; t < 4; ++t) {
            pk[t][0] = pack2_bf16(sc[t][0], sc[t][1]);
            pk[t][1] = pack2_bf16(sc[t][2], sc[t][3]);
        }
        // ---- shfl exchange -> PV B-frags (keys 0-31 -> pa0, 32-63 -> pa1) ----
        unsigned pa0[4], pa1[4];
        #pragma unroll
        for (int w = 0; w < 4; ++w) {
            const int src = col + 16*(2*(grp & 1) + (w >> 1));
            const unsigned v0 = (unsigned)__shfl((int)pk[0][w & 1], src);
            const unsigned v1 = (unsigned)__shfl((int)pk[1][w & 1], src);
            const unsigned v2 = (unsigned)__shfl((int)pk[2][w & 1], src);
            const unsigned v3 = (unsigned)__shfl((int)pk[3][w & 1], src);
            pa0[w] = (grp & 2) ? v1 : v0;
            pa1[w] = (grp & 2) ? v3 : v2;
        }
        const short8 paf0 = __builtin_bit_cast(short8, (u32x4){pa0[0], pa0[1], pa0[2], pa0[3]});
        const short8 paf1 = __builtin_bit_cast(short8, (u32x4){pa1[0], pa1[1], pa1[2], pa1[3]});
        // ---- PV: OT[d][q] accumulate ----
        {
            const short* vr0 = vbase + (size_t)(col)*S_ + k0 + grp*8;
            const short8 vf0 = *(const short8*)(vr0);
            const short8 vf1 = *(const short8*)(vr0 + 32);
            ot0 = __builtin_amdgcn_mfma_f32_16x16x32_bf16(vf0, paf0, ot0, 0, 0, 0);
            ot0 = __builtin_amdgcn_mfma_f32_16x16x32_bf16(vf1, paf1, ot0, 0, 0, 0);
            const short* vr1 = vbase + (size_t)(16 + col)*S_ + k0 + grp*8;
            const short8 vf2 = *(const short8*)(vr1);
            const short8 vf3 = *(const short8*)(vr1 + 32);
            ot1 = __builtin_amdgcn_mfma_f32_16x16x32_bf16(vf2, paf0, ot1, 0, 0, 0);
            ot1 = __builtin_amdgcn_mfma_f32_16x16x32_bf16(vf3, paf1, ot1, 0, 0, 0);
        }
    }
    const float inv = 1.0f / l;
    float* orow = attn_out + ((size_t)b*S_ + q0 + col)*E_ + h*D_ + grp*4;
    f32x4 w0, w1;
    #pragma unroll
    for (int r = 0; r < 4; ++r) { w0[r] = ot0[r]*inv; w1[r] = ot1[r]*inv; }
    *(f32x4*)(orow)      = w0;   // d block 0
    *(f32x4*)(orow + 16) = w1;   // d block 1
}

// ---------------- fp32 tiled GEMM, fused bias/relu/residual ----------------
template<int RELU, int RESID>
__global__ __launch_bounds__(256) void gemm_kernel(
    const float* __restrict__ A, const float* __restrict__ W,
    const float* __restrict__ bias, const float* __restrict__ R,
    float* __restrict__ C, int M, int N, int K)
{
    __shared__ float As[16][128];
    __shared__ float Bs[16][128];
    const int tid = threadIdx.x;
    const int tx = tid & 15, ty = tid >> 4;
    const int bm = blockIdx.y, bn = blockIdx.x;

    float acc[8][8] = {};

    for (int kb = 0; kb < K; kb += 16) {
        #pragma unroll
        for (int t = 0; t < 2; ++t) {
            const int idx = tid + t*256;
            const int r = idx >> 2, c = (idx & 3) * 4;
            const float4 a4 = *(const float4*)(A + (size_t)(bm*128 + r)*K + kb + c);
            As[c+0][r] = a4.x; As[c+1][r] = a4.y; As[c+2][r] = a4.z; As[c+3][r] = a4.w;
            const int rb = idx >> 5, cb = (idx & 31) * 4;
            *(float4*)(&Bs[rb][cb]) = *(const float4*)(W + (size_t)(kb + rb)*N + bn*128 + cb);
        }
        __syncthreads();
        #pragma unroll
        for (int kk = 0; kk < 16; ++kk) {
            float a[8], b[8];
            *(float4*)(a+0) = *(const float4*)(&As[kk][ty*4]);
            *(float4*)(a+4) = *(const float4*)(&As[kk][64 + ty*4]);
            *(float4*)(b+0) = *(const float4*)(&Bs[kk][tx*4]);
            *(float4*)(b+4) = *(const float4*)(&Bs[kk][64 + tx*4]);
            #pragma unroll
            for (int i = 0; i < 8; ++i) {
                #pragma unroll
                for (int j = 0; j < 8; ++j) acc[i][j] += a[i]*b[j];
            }
        }
        __syncthreads();
    }

    #pragma unroll
    for (int qi = 0; qi < 2; ++qi) {
        #pragma unroll
        for (int i = 0; i < 4; ++i) {
            const int m = bm*128 + qi*64 + ty*4 + i;
            #pragma unroll
            for (int qj = 0; qj < 2; ++qj) {
                const int n = bn*128 + qj*64 + tx*4;
                float4 o;
                o.x = acc[qi*4+i][qj*4+0] + bias[n+0];
                o.y = acc[qi*4+i][qj*4+1] + bias[n+1];
                o.z = acc[qi*4+i][qj*4+2] + bias[n+2];
                o.w = acc[qi*4+i][qj*4+3] + bias[n+3];
                if (RELU) {
                    o.x = fmaxf(o.x, 0.f); o.y = fmaxf(o.y, 0.f);
                    o.z = fmaxf(o.z, 0.f); o.w = fmaxf(o.w, 0.f);
                }
                if (RESID) {
                    const float4 r4 = *(const float4*)(R + (size_t)m*N + n);
                    o.x += r4.x; o.y += r4.y; o.z += r4.z; o.w += r4.w;
                }
                *(float4*)(C + (size_t)m*N + n) = o;
            }
        }
    }
}

// ---------------- series decomposition over E (window 25, edge pad) ----------------
__global__ __launch_bounds__(256) void decomp_kernel(
    const float* __restrict__ in, float* __restrict__ out)
{
    __shared__ float r[E_];
    const int row = blockIdx.x, e = threadIdx.x;
    const float xv = in[(size_t)row*E_ + e];
    r[e] = xv;
    __syncthreads();
    float sum = 0.f;
    #pragma unroll
    for (int j = -12; j <= 12; ++j) {
        int idx = e + j;
        idx = idx < 0 ? 0 : (idx > E_-1 ? E_-1 : idx);
        sum += r[idx];
    }
    out[(size_t)row*E_ + e] = xv - sum * (1.0f/25.0f);
}

extern "C" void kernel_launch(void* const* d_in, const int* in_sizes, int n_in,
                              void* d_out, int out_size, void* d_ws, size_t ws_size,
                              hipStream_t stream) {
    const float* x     = (const float*)d_in[0];
    const int*   mask  = (const int*)  d_in[1];
    const float* wq    = (const float*)d_in[2];
    const float* wk    = (const float*)d_in[3];
    const float* wv    = (const float*)d_in[4];
    const float* w_out = (const float*)d_in[5];
    const float* b_out = (const float*)d_in[6];
    const float* ff_w1 = (const float*)d_in[7];
    const float* ff_b1 = (const float*)d_in[8];
    const float* ff_w2 = (const float*)d_in[9];
    const float* ff_b2 = (const float*)d_in[10];
    const float* pr_w1 = (const float*)d_in[11];
    const float* pr_b1 = (const float*)d_in[12];
    const float* pr_w2 = (const float*)d_in[13];
    const float* pr_b2 = (const float*)d_in[14];
    float* out = (float*)d_out;

    char* ws = (char*)d_ws;
    const size_t MB = 1024ull*1024ull;
    bf16*  qb   = (bf16*)(ws + 0*MB);     // 4MB
    bf16*  kbf  = (bf16*)(ws + 4*MB);     // 4MB
    bf16*  vbf  = (bf16*)(ws + 8*MB);     // 4MB
    bf16*  vtb  = (bf16*)(ws + 12*MB);    // 4MB
    float* attn = (float*)(ws + 16*MB);   // 8MB
    float* x1   = (float*)(ws + 24*MB);   // 8MB
    float* y    = (float*)(ws + 32*MB);   // 8MB
    float* h1   = (float*)(ws + 0*MB);    // 32MB (qkv/attn buffers dead)
    float* sbuf = (float*)(ws + 40*MB);   // 8MB
    float* s2   = (float*)(ws + 0*MB);    // 8MB  (h1 dead)
    float* h2   = (float*)(ws + 8*MB);    // 32MB (8..40MB; s2 live at 0..8)

    // 1. QKV (bf16) + V transpose
    qkv_kernel<<<NTOK/16, 256, 0, stream>>>(x, wq, wk, wv, qb, kbf, vbf);
    vtrans_kernel<<<B_*H_*(S_/256), 256, 0, stream>>>((const short*)vbf, (short*)vtb);
    // 2. MFMA flash attention
    attn_mfma_kernel<<<B_*H_*S_/64, 256, 0, stream>>>(
        (const short*)qb, (const short*)kbf, (const short*)vtb, mask, attn);
    // 3. out-proj + residual
    dim3 gE(E_/128, NTOK/128);
    gemm_kernel<0,1><<<gE, 256, 0, stream>>>(attn, w_out, b_out, x, x1, NTOK, E_, E_);
    // 4. decomposition 1
    decomp_kernel<<<NTOK, 256, 0, stream>>>(x1, y);
    // 5. FFN
    dim3 gF(FF_/128, NTOK/128);
    gemm_kernel<1,0><<<gF, 256, 0, stream>>>(y, ff_w1, ff_b1, nullptr, h1, NTOK, FF_, E_);
    gemm_kernel<0,1><<<gE, 256, 0, stream>>>(h1, ff_w2, ff_b2, y, sbuf, NTOK, E_, FF_);
    // 6. decomposition 2
    decomp_kernel<<<NTOK, 256, 0, stream>>>(sbuf, s2);
    // 7. projection FFN -> out
    gemm_kernel<1,0><<<gF, 256, 0, stream>>>(s2, pr_w1, pr_b1, nullptr, h2, NTOK, FF_, E_);
    gemm_kernel<0,0><<<gE, 256, 0, stream>>>(h2, pr_w2, pr_b2, nullptr, out, NTOK, E_, FF_);
}

// Round 3
// 231.048 us; speedup vs baseline: 5.9181x; 2.3113x over previous
//
#include <hip/hip_runtime.h>
#include <hip/hip_bf16.h>
#include <math.h>

#define B_   4
#define S_   2048
#define E_   256
#define H_   8
#define D_   32
#define FF_  1024
#define NTOK (B_*S_)   // 8192

typedef __attribute__((ext_vector_type(8))) short short8;
typedef __attribute__((ext_vector_type(4))) float f32x4;
typedef __attribute__((ext_vector_type(4))) unsigned u32x4;
typedef __hip_bfloat16 bf16;

__device__ __forceinline__ unsigned pack2_bf16(float a, float b) {
    unsigned ua = __builtin_bit_cast(unsigned, a);
    unsigned ub = __builtin_bit_cast(unsigned, b);
    ua = (ua + 0x7fffu + ((ua >> 16) & 1u)) >> 16;
    ub = (ub + 0x7fffu + ((ub >> 16) & 1u)) >> 16;
    return ua | (ub << 16);
}
__device__ __forceinline__ unsigned short round_bf16(float a) {
    unsigned ua = __builtin_bit_cast(unsigned, a);
    return (unsigned short)((ua + 0x7fffu + ((ua >> 16) & 1u)) >> 16);
}
__device__ __forceinline__ void gld16(const short* g, short* l) {
    __builtin_amdgcn_global_load_lds(
        (const __attribute__((address_space(1))) unsigned int*)g,
        (__attribute__((address_space(3))) unsigned int*)l, 16, 0, 0);
}
// LDS tile layout: row stride 64 shorts (128B); 16B slot index = c16 ^ (row&7)
__device__ __forceinline__ short8 lds_frag(const short* base, int r, int c16) {
    return *(const short8*)(base + r*64 + (((c16) ^ (r & 7)) << 3));
}

// ---------------- weight convert+transpose: w[K][N] f32 -> wt[N][K] bf16 ----------------
__global__ __launch_bounds__(256) void wconv_kernel(
    const float* __restrict__ w, unsigned short* __restrict__ wt, int K, int N)
{
    __shared__ float tile[32][33];
    const int n0 = blockIdx.x * 32, k0 = blockIdx.y * 32;
    const int c = threadIdx.x & 31, r0 = threadIdx.x >> 5;   // r0: 0..7
    #pragma unroll
    for (int i = 0; i < 4; ++i)
        tile[r0 + 8*i][c] = w[(size_t)(k0 + r0 + 8*i)*N + n0 + c];
    __syncthreads();
    #pragma unroll
    for (int i = 0; i < 4; ++i)
        wt[(size_t)(n0 + r0 + 8*i)*K + k0 + c] = round_bf16(tile[c][r0 + 8*i]);
}

// ---------------- QKV projection -> bf16 [B,H,S,D] ----------------
__global__ __launch_bounds__(256) void qkv_kernel(
    const float* __restrict__ x,
    const float* __restrict__ wq, const float* __restrict__ wk, const float* __restrict__ wv,
    bf16* __restrict__ q, bf16* __restrict__ k, bf16* __restrict__ v)
{
    __shared__ float wqs[D_*D_], wks[D_*D_], wvs[D_*D_];
    __shared__ float xs[E_];
    const int tid = threadIdx.x;
    for (int i = tid; i < D_*D_; i += 256) {
        wqs[i] = wq[i]; wks[i] = wk[i]; wvs[i] = wv[i];
    }
    const int h = tid >> 5, d = tid & 31;
    const int tok0 = blockIdx.x * 16;
    for (int t = 0; t < 16; ++t) {
        const int tok = tok0 + t;
        __syncthreads();
        xs[tid] = x[(size_t)tok*E_ + tid];
        __syncthreads();
        float aq = 0.f, ak = 0.f, av = 0.f;
        #pragma unroll
        for (int i = 0; i < D_; ++i) {
            const float xv = xs[h*D_ + i];
            aq += xv * wqs[i*D_ + d];
            ak += xv * wks[i*D_ + d];
            av += xv * wvs[i*D_ + d];
        }
        const int b = tok >> 11;
        const int s = tok & (S_-1);
        const size_t o = ((size_t)(b*H_ + h)*S_ + s)*D_ + d;
        q[o] = __float2bfloat16(aq);
        k[o] = __float2bfloat16(ak);
        v[o] = __float2bfloat16(av);
    }
}

// ---------------- V transpose: [B,H,S,D] -> VT [B,H,D,S] ----------------
__global__ __launch_bounds__(256) void vtrans_kernel(
    const short* __restrict__ v, short* __restrict__ vt)
{
    __shared__ short t2[D_][256];
    const int tid = threadIdx.x;
    const int bh = blockIdx.x >> 3;
    const int s0 = (blockIdx.x & 7) * 256;
    const short* src = v + ((size_t)bh*S_ + s0 + tid)*D_;
    const short8 r0 = *(const short8*)(src);
    const short8 r1 = *(const short8*)(src + 8);
    const short8 r2 = *(const short8*)(src + 16);
    const short8 r3 = *(const short8*)(src + 24);
    #pragma unroll
    for (int i = 0; i < 8; ++i) {
        t2[i     ][tid] = r0[i];
        t2[i + 8 ][tid] = r1[i];
        t2[i + 16][tid] = r2[i];
        t2[i + 24][tid] = r3[i];
    }
    __syncthreads();
    const int d = tid >> 3, j = tid & 7;
    short* dst = vt + ((size_t)(bh*D_ + d))*S_ + s0 + j*32;
    const short8* row = (const short8*)&t2[d][j*32];
    const short8 o0 = row[0], o1 = row[1], o2 = row[2], o3 = row[3];
    *(short8*)(dst     ) = o0;
    *(short8*)(dst + 8 ) = o1;
    *(short8*)(dst + 16) = o2;
    *(short8*)(dst + 24) = o3;
}

// ---------------- MFMA flash attention (bf16 out) ----------------
__global__ __launch_bounds__(256) void attn_mfma_kernel(
    const short* __restrict__ qg, const short* __restrict__ kg,
    const short* __restrict__ vtg, const int* __restrict__ mask,
    unsigned short* __restrict__ attn_out)
{
    const int lane = threadIdx.x & 63;
    const int wid  = threadIdx.x >> 6;
    const int col  = lane & 15;
    const int grp  = lane >> 4;
    const int bh   = (int)blockIdx.x >> 5;
    const int qt   = (int)blockIdx.x & 31;
    const int b    = bh >> 3;
    const int h    = bh & 7;
    const int q0   = qt*64 + wid*16;

    const short8 qf = *(const short8*)(qg + ((size_t)bh*S_ + q0 + col)*D_ + grp*8);
    const short* kbase = kg  + (size_t)bh*S_*D_;
    const short* vbase = vtg + (size_t)bh*D_*S_;
    const int*   mrow  = mask + b*S_;

    f32x4 ot0 = {0.f,0.f,0.f,0.f}, ot1 = {0.f,0.f,0.f,0.f};
    const f32x4 zero = {0.f,0.f,0.f,0.f};
    float m = -3.0e38f, l = 0.f;

    for (int k0 = 0; k0 < S_; k0 += 64) {
        f32x4 s[4];
        #pragma unroll
        for (int t = 0; t < 4; ++t) {
            const short8 kf = *(const short8*)(kbase + (size_t)(k0 + t*16 + col)*D_ + grp*8);
            s[t] = __builtin_amdgcn_mfma_f32_16x16x32_bf16(kf, qf, zero, 0, 0, 0);
        }
        float sc[4][4];
        float pmax = -3.0e38f;
        #pragma unroll
        for (int t = 0; t < 4; ++t) {
            #pragma unroll
            for (int r = 0; r < 4; ++r) {
                float z = s[t][r] * 0.0625f;
                if (mrow[k0 + t*16 + grp*4 + r] == 0) z = -1e20f;
                sc[t][r] = z;
                pmax = fmaxf(pmax, z);
            }
        }
        pmax = fmaxf(pmax, __shfl_xor(pmax, 16));
        pmax = fmaxf(pmax, __shfl_xor(pmax, 32));
        if (!__all(pmax - m <= 8.0f)) {
            const float mn = fmaxf(m, pmax);
            const float al = __expf(m - mn);
            l *= al;
            #pragma unroll
            for (int r = 0; r < 4; ++r) { ot0[r] *= al; ot1[r] *= al; }
            m = mn;
        }
        float ps = 0.f;
        #pragma unroll
        for (int t = 0; t < 4; ++t) {
            #pragma unroll
            for (int r = 0; r < 4; ++r) {
                sc[t][r] = __expf(sc[t][r] - m);
                ps += sc[t][r];
            }
        }
        ps += __shfl_xor(ps, 16);
        ps += __shfl_xor(ps, 32);
        l += ps;
        unsigned pk[4][2];
        #pragma unroll
        for (int t = 0; t < 4; ++t) {
            pk[t][0] = pack2_bf16(sc[t][0], sc[t][1]);
            pk[t][1] = pack2_bf16(sc[t][2], sc[t][3]);
        }
        unsigned pa0[4], pa1[4];
        #pragma unroll
        for (int w = 0; w < 4; ++w) {
            const int src = col + 16*(2*(grp & 1) + (w >> 1));
            const unsigned v0 = (unsigned)__shfl((int)pk[0][w & 1], src);
            const unsigned v1 = (unsigned)__shfl((int)pk[1][w & 1], src);
            const unsigned v2 = (unsigned)__shfl((int)pk[2][w & 1], src);
            const unsigned v3 = (unsigned)__shfl((int)pk[3][w & 1], src);
            pa0[w] = (grp & 2) ? v1 : v0;
            pa1[w] = (grp & 2) ? v3 : v2;
        }
        const short8 paf0 = __builtin_bit_cast(short8, (u32x4){pa0[0], pa0[1], pa0[2], pa0[3]});
        const short8 paf1 = __builtin_bit_cast(short8, (u32x4){pa1[0], pa1[1], pa1[2], pa1[3]});
        {
            const short* vr0 = vbase + (size_t)(col)*S_ + k0 + grp*8;
            const short8 vf0 = *(const short8*)(vr0);
            const short8 vf1 = *(const short8*)(vr0 + 32);
            ot0 = __builtin_amdgcn_mfma_f32_16x16x32_bf16(vf0, paf0, ot0, 0, 0, 0);
            ot0 = __builtin_amdgcn_mfma_f32_16x16x32_bf16(vf1, paf1, ot0, 0, 0, 0);
            const short* vr1 = vbase + (size_t)(16 + col)*S_ + k0 + grp*8;
            const short8 vf2 = *(const short8*)(vr1);
            const short8 vf3 = *(const short8*)(vr1 + 32);
            ot1 = __builtin_amdgcn_mfma_f32_16x16x32_bf16(vf2, paf0, ot1, 0, 0, 0);
            ot1 = __builtin_amdgcn_mfma_f32_16x16x32_bf16(vf3, paf1, ot1, 0, 0, 0);
        }
    }
    const float inv = 1.0f / l;
    unsigned short* orow = attn_out + ((size_t)b*S_ + q0 + col)*E_ + h*D_ + grp*4;
    uint2 o0, o1;
    o0.x = pack2_bf16(ot0[0]*inv, ot0[1]*inv);
    o0.y = pack2_bf16(ot0[2]*inv, ot0[3]*inv);
    o1.x = pack2_bf16(ot1[0]*inv, ot1[1]*inv);
    o1.y = pack2_bf16(ot1[2]*inv, ot1[3]*inv);
    *(uint2*)(orow)      = o0;
    *(uint2*)(orow + 16) = o1;
}

// ---------------- bf16 MFMA GEMM: C[M,N] = op(A[M,K] @ WT[N,K]^T + bias) ----------------
// BM=128, BK=64, 256 thr = 4 waves (2x2). global_load_lds + XOR slot swizzle.
template<int BN, int RELU, int RESID, int WF32, int WBF16>
__global__ __launch_bounds__(256) void mgemm_kernel(
    const short* __restrict__ A, const short* __restrict__ WT,
    const float* __restrict__ bias, const float* __restrict__ R,
    float* __restrict__ C32, unsigned short* __restrict__ Cb,
    int M, int N, int K)
{
    constexpr int FC = BN / 32;
    __shared__ alignas(16) short As[128*64];
    __shared__ alignas(16) short Bs[BN*64];
    const int t = threadIdx.x, w = t >> 6, lane = t & 63;
    const int col = lane & 15, grp = lane >> 4;
    const int wm = w >> 1, wn = w & 1;
    const int bm = blockIdx.y, bn = blockIdx.x;
    const int arow = t >> 3, ac = t & 7;

    f32x4 acc[4][FC];
    #pragma unroll
    for (int i = 0; i < 4; ++i)
        #pragma unroll
        for (int j = 0; j < FC; ++j) acc[i][j] = (f32x4){0.f,0.f,0.f,0.f};

    for (int kb = 0; kb < K; kb += 64) {
        #pragma unroll
        for (int b2 = 0; b2 < 4; ++b2) {
            const int row = b2*32 + arow;
            gld16(A + (size_t)(bm*128 + row)*K + kb + ((ac ^ (row & 7)) << 3),
                  As + b2*2048 + w*512);
        }
        #pragma unroll
        for (int b2 = 0; b2 < BN/32; ++b2) {
            const int row = b2*32 + arow;
            gld16(WT + (size_t)(bn*BN + row)*K + kb + ((ac ^ (row & 7)) << 3),
                  Bs + b2*2048 + w*512);
        }
        __syncthreads();
        #pragma unroll
        for (int s = 0; s < 2; ++s) {
            short8 af[4], bf_[FC];
            #pragma unroll
            for (int fr = 0; fr < 4; ++fr)
                af[fr] = lds_frag(As, wm*64 + fr*16 + col, s*4 + grp);
            #pragma unroll
            for (int fc = 0; fc < FC; ++fc)
                bf_[fc] = lds_frag(Bs, wn*(BN/2) + fc*16 + col, s*4 + grp);
            #pragma unroll
            for (int fr = 0; fr < 4; ++fr)
                #pragma unroll
                for (int fc = 0; fc < FC; ++fc)
                    acc[fr][fc] = __builtin_amdgcn_mfma_f32_16x16x32_bf16(af[fr], bf_[fc], acc[fr][fc], 0, 0, 0);
        }
        __syncthreads();
    }

    #pragma unroll
    for (int fc = 0; fc < FC; ++fc) {
        const int n = bn*BN + wn*(BN/2) + fc*16 + col;
        const float bs = bias[n];
        #pragma unroll
        for (int fr = 0; fr < 4; ++fr) {
            #pragma unroll
            for (int reg = 0; reg < 4; ++reg) {
                const int m = bm*128 + wm*64 + fr*16 + grp*4 + reg;
                float v = acc[fr][fc][reg] + bs;
                if (RELU) v = fmaxf(v, 0.f);
                if (RESID) v += R[(size_t)m*N + n];
                if (WF32) C32[(size_t)m*N + n] = v;
                if (WBF16) Cb[(size_t)m*N + n] = round_bf16(v);
            }
        }
    }
}

// ---------------- series decomposition over E (window 25, edge pad) ----------------
template<int WF32, int WBF16>
__global__ __launch_bounds__(256) void decomp_kernel(
    const float* __restrict__ in, float* __restrict__ o32, unsigned short* __restrict__ ob)
{
    __shared__ float r[E_];
    const int row = blockIdx.x, e = threadIdx.x;
    const float xv = in[(size_t)row*E_ + e];
    r[e] = xv;
    __syncthreads();
    float sum = 0.f;
    #pragma unroll
    for (int j = -12; j <= 12; ++j) {
        int idx = e + j;
        idx = idx < 0 ? 0 : (idx > E_-1 ? E_-1 : idx);
        sum += r[idx];
    }
    const float res = xv - sum * (1.0f/25.0f);
    if (WF32) o32[(size_t)row*E_ + e] = res;
    if (WBF16) ob[(size_t)row*E_ + e] = round_bf16(res);
}

extern "C" void kernel_launch(void* const* d_in, const int* in_sizes, int n_in,
                              void* d_out, int out_size, void* d_ws, size_t ws_size,
                              hipStream_t stream) {
    const float* x     = (const float*)d_in[0];
    const int*   mask  = (const int*)  d_in[1];
    const float* wq    = (const float*)d_in[2];
    const float* wk    = (const float*)d_in[3];
    const float* wv    = (const float*)d_in[4];
    const float* w_out = (const float*)d_in[5];
    const float* b_out = (const float*)d_in[6];
    const float* ff_w1 = (const float*)d_in[7];
    const float* ff_b1 = (const float*)d_in[8];
    const float* ff_w2 = (const float*)d_in[9];
    const float* ff_b2 = (const float*)d_in[10];
    const float* pr_w1 = (const float*)d_in[11];
    const float* pr_b1 = (const float*)d_in[12];
    const float* pr_w2 = (const float*)d_in[13];
    const float* pr_b2 = (const float*)d_in[14];
    float* out = (float*)d_out;

    char* ws = (char*)d_ws;
    const size_t MB = 1024ull*1024ull;
    const size_t KB = 1024ull;
    bf16*  qb    = (bf16*)(ws + 0*MB);
    bf16*  kbf   = (bf16*)(ws + 4*MB);
    bf16*  vbf   = (bf16*)(ws + 8*MB);
    bf16*  vtb   = (bf16*)(ws + 12*MB);
    unsigned short* attnb = (unsigned short*)(ws + 16*MB);   // 4MB bf16
    float* x1    = (float*)(ws + 20*MB);                     // 8MB
    float* y32   = (float*)(ws + 28*MB);                     // 8MB
    unsigned short* yb  = (unsigned short*)(ws + 36*MB);     // 4MB
    unsigned short* h1  = (unsigned short*)(ws + 0*MB);      // 16MB (qkv dead)
    float* s32   = (float*)(ws + 20*MB);                     // 8MB (x1 dead)
    unsigned short* s2b = (unsigned short*)(ws + 16*MB);     // 4MB (attnb dead)
    unsigned short* h2  = (unsigned short*)(ws + 0*MB);      // 16MB (h1 dead)
    unsigned short* woT = (unsigned short*)(ws + 40*MB);                // 128KB [256][256]
    unsigned short* f1T = (unsigned short*)(ws + 40*MB + 128*KB);       // 512KB [1024][256]
    unsigned short* f2T = (unsigned short*)(ws + 40*MB + 640*KB);       // 512KB [256][1024]
    unsigned short* p1T = (unsigned short*)(ws + 40*MB + 1152*KB);      // 512KB [1024][256]
    unsigned short* p2T = (unsigned short*)(ws + 40*MB + 1664*KB);      // 512KB [256][1024]

    // 0. weight convert+transpose (bf16)
    wconv_kernel<<<dim3(E_/32,  E_/32),  256, 0, stream>>>(w_out, woT, E_,  E_);
    wconv_kernel<<<dim3(FF_/32, E_/32),  256, 0, stream>>>(ff_w1, f1T, E_,  FF_);
    wconv_kernel<<<dim3(E_/32,  FF_/32), 256, 0, stream>>>(ff_w2, f2T, FF_, E_);
    wconv_kernel<<<dim3(FF_/32, E_/32),  256, 0, stream>>>(pr_w1, p1T, E_,  FF_);
    wconv_kernel<<<dim3(E_/32,  FF_/32), 256, 0, stream>>>(pr_w2, p2T, FF_, E_);
    // 1. QKV (bf16) + V transpose
    qkv_kernel<<<NTOK/16, 256, 0, stream>>>(x, wq, wk, wv, qb, kbf, vbf);
    vtrans_kernel<<<B_*H_*(S_/256), 256, 0, stream>>>((const short*)vbf, (short*)vtb);
    // 2. MFMA flash attention -> bf16
    attn_mfma_kernel<<<B_*H_*S_/64, 256, 0, stream>>>(
        (const short*)qb, (const short*)kbf, (const short*)vtb, mask, attnb);
    // 3. out-proj + residual: x1 = x + attn @ w_out + b_out   (fp32 out)
    mgemm_kernel<64,0,1,1,0><<<dim3(E_/64, NTOK/128), 256, 0, stream>>>(
        (const short*)attnb, (const short*)woT, b_out, x, x1, nullptr, NTOK, E_, E_);
    // 4. decomposition 1: y (fp32 + bf16)
    decomp_kernel<1,1><<<NTOK, 256, 0, stream>>>(x1, y32, yb);
    // 5. FFN: h1 = relu(y @ ff_w1 + b1)  (bf16 out)
    mgemm_kernel<128,1,0,0,1><<<dim3(FF_/128, NTOK/128), 256, 0, stream>>>(
        (const short*)yb, (const short*)f1T, ff_b1, nullptr, nullptr, h1, NTOK, FF_, E_);
    //    s = y + h1 @ ff_w2 + b2  (fp32 out)
    mgemm_kernel<64,0,1,1,0><<<dim3(E_/64, NTOK/128), 256, 0, stream>>>(
        (const short*)h1, (const short*)f2T, ff_b2, y32, s32, nullptr, NTOK, E_, FF_);
    // 6. decomposition 2: s2 (bf16 only)
    decomp_kernel<0,1><<<NTOK, 256, 0, stream>>>(s32, nullptr, s2b);
    // 7. projection FFN
    mgemm_kernel<128,1,0,0,1><<<dim3(FF_/128, NTOK/128), 256, 0, stream>>>(
        (const short*)s2b, (const short*)p1T, pr_b1, nullptr, nullptr, h2, NTOK, FF_, E_);
    mgemm_kernel<64,0,0,1,0><<<dim3(E_/64, NTOK/128), 256, 0, stream>>>(
        (const short*)h2, (const short*)p2T, pr_b2, nullptr, out, nullptr, NTOK, E_, FF_);
}